// Round 4
// baseline (217.150 us; speedup 1.0000x reference)
//
#include <hip/hip_runtime.h>

// Involution: B=16, C=256, H=W=56, mid=64, GROUPS=16, GROUP_SIZE=16, K=3 (KK=9)
// All fp32. Output (16,256,56,56).

#define Cn    256
#define MID   64
#define Hn    56
#define Wn    56
#define HW    3136
#define Bn    16
#define NPIX  (Bn * HW)       // 50176
#define CHW   (Cn * HW)
#define NKK   9
#define NG    16
#define GSZ   16
#define PXT   64              // pixels per block (49 blocks/batch, batch-aligned)
#define LTP   68              // lt row pitch (pad: 16B-aligned, conflict-benign)
#define BN_EPS 1e-5f

// ---------------------------------------------------------------------------
// prep: w1f[c*64+o] = w1[o*256+c] * scale[o];  bias1[o] = beta[o]-mean[o]*scale[o]
// ---------------------------------------------------------------------------
__global__ __launch_bounds__(256) void prep_kernel(
    const float* __restrict__ w1,
    const float* __restrict__ gamma,
    const float* __restrict__ beta,
    const float* __restrict__ mean,
    const float* __restrict__ var,
    float* __restrict__ w1f,
    float* __restrict__ bias1) {
  int idx = blockIdx.x * 256 + threadIdx.x;
  if (idx < MID * Cn) {
    int c = idx >> 6;
    int o = idx & 63;
    float scale = gamma[o] / sqrtf(var[o] + BN_EPS);
    w1f[idx] = w1[o * Cn + c] * scale;
  } else if (idx < MID * Cn + MID) {
    int o = idx - MID * Cn;
    float scale = gamma[o] / sqrtf(var[o] + BN_EPS);
    bias1[o] = beta[o] - mean[o] * scale;
  }
}

// ---------------------------------------------------------------------------
// conv1: t[o][gp] = relu(bias1[o] + sum_c x[b,c,hw] * w1f[c][o])
// Block = 64 px * 64 outputs, 512 threads (8 waves, 8 outputs each).
// x double-buffered through LDS (read exactly once from global).
// ---------------------------------------------------------------------------
__global__ __launch_bounds__(512, 8) void conv1_kernel(
    const float* __restrict__ x,
    const float* __restrict__ w1f,
    const float* __restrict__ bias1,
    float* __restrict__ t) {
  __shared__ float lx[2][16][PXT];     // 2 x 4 KB

  int tid = threadIdx.x;
  int px  = tid & 63;
  int ocv = tid >> 6;                              // 0..7 (wave id)
  int oc  = __builtin_amdgcn_readfirstlane(ocv);

  int px0 = blockIdx.x * PXT;
  int b   = px0 / HW;
  const float* xb = x + (size_t)b * CHW + (px0 - b * HW) + px;

  float r[2];
#pragma unroll
  for (int j = 0; j < 2; ++j) r[j] = xb[(size_t)(ocv * 2 + j) * HW];
#pragma unroll
  for (int j = 0; j < 2; ++j) lx[0][ocv * 2 + j][px] = r[j];
  __syncthreads();

  float acc[8];
#pragma unroll
  for (int j = 0; j < 8; ++j) acc[j] = 0.0f;

  for (int k = 0; k < 16; ++k) {       // 16 c-tiles of 16
    int cur = k & 1;
    if (k < 15) {
#pragma unroll
      for (int j = 0; j < 2; ++j)
        r[j] = xb[(size_t)((k + 1) * 16 + ocv * 2 + j) * HW];
    }
#pragma unroll
    for (int c = 0; c < 16; ++c) {
      float xv = lx[cur][c][px];
      const float* wr = w1f + ((k * 16 + c) << 6) + (oc << 3);  // uniform
#pragma unroll
      for (int q = 0; q < 2; ++q) {
        float4 w4 = *(const float4*)(wr + q * 4);
        acc[q * 4 + 0] = fmaf(xv, w4.x, acc[q * 4 + 0]);
        acc[q * 4 + 1] = fmaf(xv, w4.y, acc[q * 4 + 1]);
        acc[q * 4 + 2] = fmaf(xv, w4.z, acc[q * 4 + 2]);
        acc[q * 4 + 3] = fmaf(xv, w4.w, acc[q * 4 + 3]);
      }
    }
    if (k < 15) {
#pragma unroll
      for (int j = 0; j < 2; ++j) lx[1 - cur][ocv * 2 + j][px] = r[j];
    }
    __syncthreads();
  }

#pragma unroll
  for (int j = 0; j < 8; ++j) {
    int o = oc * 8 + j;
    t[(size_t)o * NPIX + px0 + px] = fmaxf(acc[j] + bias1[o], 0.0f);
  }
}

// ---------------------------------------------------------------------------
// conv2 + involution fused. Block = 64 px, 512 threads (8 waves).
// Wave w handles groups {2w, 2w+1} for all 64 px.
// Phase 1: stage t[px][o] in LDS (t read once from global; b128 readback).
// Phase 2: 18 per-pixel kernel weights in REGISTERS (no LDS round-trip).
// Phase 3: involution, 36-deep load batches.
// ---------------------------------------------------------------------------
__global__ __launch_bounds__(512, 5) void conv2_inv_kernel(
    const float* __restrict__ x,
    const float* __restrict__ t,
    const float* __restrict__ w2,
    const float* __restrict__ b2,
    float* __restrict__ out) {
  __shared__ float lt[PXT][LTP];        // 17 KB

  int tid = threadIdx.x;
  int px  = tid & 63;
  int wvv = tid >> 6;                              // 0..7
  int wvu = __builtin_amdgcn_readfirstlane(wvv);

  int px0 = blockIdx.x * PXT;
  int b   = px0 / HW;
  int hw0 = px0 - b * HW;

  // ---- phase 1: stage t tile, transposed to [px][o] ----
#pragma unroll
  for (int j = 0; j < 8; ++j) {
    int o = wvv * 8 + j;                // wave-uniform o, coalesced over px
    lt[px][o] = t[(size_t)o * NPIX + px0 + px];
  }
  __syncthreads();

  // ---- phase 2: 2 groups x 9 kernel weights per thread, in registers ----
  float a[2][9];
#pragma unroll
  for (int gi = 0; gi < 2; ++gi)
#pragma unroll
    for (int kk = 0; kk < NKK; ++kk)
      a[gi][kk] = b2[(wvu * 2 + gi) * NKK + kk];

#pragma unroll
  for (int half = 0; half < 2; ++half) {
    float tr[32];
#pragma unroll
    for (int q = 0; q < 8; ++q)
      *(float4*)&tr[q * 4] = *(const float4*)&lt[px][half * 32 + q * 4];

#pragma unroll
    for (int gi = 0; gi < 2; ++gi) {
      int g = wvu * 2 + gi;
#pragma unroll
      for (int kk = 0; kk < NKK; ++kk) {
        const float4* wr = (const float4*)(w2 + (g * NKK + kk) * MID + half * 32);
        float s = a[gi][kk];
#pragma unroll
        for (int q = 0; q < 8; ++q) {
          float4 w4 = wr[q];
          s = fmaf(tr[q * 4 + 0], w4.x, s);
          s = fmaf(tr[q * 4 + 1], w4.y, s);
          s = fmaf(tr[q * 4 + 2], w4.z, s);
          s = fmaf(tr[q * 4 + 3], w4.w, s);
        }
        a[gi][kk] = s;
      }
    }
  }

  // ---- phase 3: involution ----
  int hw = hw0 + px;
  int h  = hw / Wn;
  int w  = hw - h * Wn;

  int off[NKK];
  unsigned vmask = 0;
#pragma unroll
  for (int kk = 0; kk < NKK; ++kk) {
    int di = kk / 3 - 1;
    int dj = kk % 3 - 1;
    int h2 = h + di;
    int w2v = w + dj;
    bool valid = ((unsigned)h2 < (unsigned)Hn) && ((unsigned)w2v < (unsigned)Wn);
    off[kk] = valid ? (h2 * Wn + w2v) : hw;
    vmask |= (valid ? 1u : 0u) << kk;
  }

  const float* xb = x + (size_t)b * CHW;
  float* ob = out + (size_t)b * CHW + hw;

#pragma unroll
  for (int gi = 0; gi < 2; ++gi) {
    int g = wvu * 2 + gi;
    float wk[NKK];
#pragma unroll
    for (int kk = 0; kk < NKK; ++kk)
      wk[kk] = ((vmask >> kk) & 1u) ? a[gi][kk] : 0.0f;

    const float* xg = xb + (size_t)(g * GSZ) * HW;
#pragma unroll
    for (int c4 = 0; c4 < 4; ++c4) {
      float xv[4][NKK];
#pragma unroll
      for (int cc = 0; cc < 4; ++cc) {
        const float* xc = xg + (size_t)(c4 * 4 + cc) * HW;
#pragma unroll
        for (int kk = 0; kk < NKK; ++kk)
          xv[cc][kk] = xc[off[kk]];
      }
#pragma unroll
      for (int cc = 0; cc < 4; ++cc) {
        float s = 0.0f;
#pragma unroll
        for (int kk = 0; kk < NKK; ++kk)
          s = fmaf(wk[kk], xv[cc][kk], s);
        ob[(size_t)(g * GSZ + c4 * 4 + cc) * HW] = s;
      }
    }
  }
}

// ---------------------------------------------------------------------------
extern "C" void kernel_launch(void* const* d_in, const int* in_sizes, int n_in,
                              void* d_out, int out_size, void* d_ws, size_t ws_size,
                              hipStream_t stream) {
  const float* x     = (const float*)d_in[0];
  const float* w1    = (const float*)d_in[1];
  const float* gamma = (const float*)d_in[2];
  const float* beta  = (const float*)d_in[3];
  const float* mean  = (const float*)d_in[4];
  const float* var   = (const float*)d_in[5];
  const float* w2    = (const float*)d_in[6];
  const float* b2    = (const float*)d_in[7];
  float* out = (float*)d_out;

  // workspace: t (64 x 50176 fp32 = 12.85 MB) | w1f (64 KB) | bias1 (256 B)
  char* ws = (char*)d_ws;
  float* t     = (float*)ws;
  float* w1f   = (float*)(ws + (size_t)MID * NPIX * 4);
  float* bias1 = (float*)(ws + (size_t)MID * NPIX * 4 + (size_t)MID * Cn * 4);

  prep_kernel<<<(MID * Cn + MID + 255) / 256, 256, 0, stream>>>(
      w1, gamma, beta, mean, var, w1f, bias1);
  conv1_kernel<<<NPIX / PXT, 512, 0, stream>>>(x, w1f, bias1, t);
  conv2_inv_kernel<<<NPIX / PXT, 512, 0, stream>>>(x, t, w2, b2, out);
}